// Round 1
// baseline (360.617 us; speedup 1.0000x reference)
//
#include <hip/hip_runtime.h>
#include <math.h>

// Edge kernel: 16 lanes cooperate per edge. Each lane loads one float4 of
// Q[c[e]] and K[u[e]] (row = 64 floats = 16 float4 = 256B coalesced segment),
// dots, reduces across the 16-lane group via shfl_xor, lane 0 atomicAdds
// exp(dot/8) into node_sum[c[e]].
__global__ __launch_bounds__(256) void pe_edge_kernel(
    const float* __restrict__ Q,
    const float* __restrict__ K,
    const int* __restrict__ c,
    const int* __restrict__ u,
    float* __restrict__ node_sum,
    int num_edges) {
    const int tid = blockIdx.x * blockDim.x + threadIdx.x;
    const int group = tid >> 4;   // 16 lanes per edge
    const int sub = tid & 15;
    const int ngroups = (gridDim.x * blockDim.x) >> 4;
    const float inv_scale = 0.125f;  // 1/sqrt(64)

    for (int e = group; e < num_edges; e += ngroups) {
        const int ci = c[e];
        const int ui = u[e];
        const float4 qv = ((const float4*)(Q + (size_t)ci * 64))[sub];
        const float4 kv = ((const float4*)(K + (size_t)ui * 64))[sub];
        float dot = qv.x * kv.x + qv.y * kv.y + qv.z * kv.z + qv.w * kv.w;
        // reduce over the 16-lane group (xor masks < 16 stay in-group)
        dot += __shfl_xor(dot, 1, 64);
        dot += __shfl_xor(dot, 2, 64);
        dot += __shfl_xor(dot, 4, 64);
        dot += __shfl_xor(dot, 8, 64);
        if (sub == 0) {
            atomicAdd(&node_sum[ci], __expf(dot * inv_scale));
        }
    }
}

// Node kernel: lse = log(node_sum[n]) (0 for empty), segment-sum into
// out[batch[n]]. batch is sorted, so most waves see a uniform graph id:
// reduce across the wave and do one atomic; fall back to per-lane atomics
// at graph boundaries.
__global__ __launch_bounds__(256) void pe_node_kernel(
    const float* __restrict__ node_sum,
    const int* __restrict__ batch,
    float* __restrict__ out,
    int num_nodes) {
    const int n = blockIdx.x * blockDim.x + threadIdx.x;
    const bool valid = (n < num_nodes);
    const int nc = valid ? n : (num_nodes - 1);

    const float s = valid ? node_sum[nc] : 0.0f;
    float lse = (s > 0.0f) ? logf(s) : 0.0f;
    if (!valid) lse = 0.0f;
    const int b = batch[nc];

    const int b0 = __shfl(b, 0, 64);
    const bool uniform = __all(b == b0);
    if (uniform) {
        // butterfly reduce lse across the 64-lane wave
        lse += __shfl_xor(lse, 1, 64);
        lse += __shfl_xor(lse, 2, 64);
        lse += __shfl_xor(lse, 4, 64);
        lse += __shfl_xor(lse, 8, 64);
        lse += __shfl_xor(lse, 16, 64);
        lse += __shfl_xor(lse, 32, 64);
        if ((threadIdx.x & 63) == 0 && lse != 0.0f) {
            atomicAdd(&out[b0], lse);
        }
    } else {
        if (valid && lse != 0.0f) {
            atomicAdd(&out[b], lse);
        }
    }
}

extern "C" void kernel_launch(void* const* d_in, const int* in_sizes, int n_in,
                              void* d_out, int out_size, void* d_ws, size_t ws_size,
                              hipStream_t stream) {
    const float* Q2 = (const float*)d_in[0];
    const float* K2 = (const float*)d_in[1];
    const int* c_2 = (const int*)d_in[2];
    const int* u_2 = (const int*)d_in[3];
    const int* batch = (const int*)d_in[4];

    const int num_nodes = in_sizes[4];   // batch has one entry per node
    const int num_edges = in_sizes[2];
    const int num_graphs = out_size;

    float* node_sum = (float*)d_ws;      // num_nodes floats
    float* out = (float*)d_out;          // num_graphs floats

    // ws/out are poisoned 0xAA before every timed launch — zero them here.
    hipMemsetAsync(node_sum, 0, (size_t)num_nodes * sizeof(float), stream);
    hipMemsetAsync(out, 0, (size_t)num_graphs * sizeof(float), stream);

    // Edge pass: grid-stride, 16 lanes/edge.
    {
        const int block = 256;
        const int grid = 16384;  // 262144 groups, ~12 edges each
        pe_edge_kernel<<<grid, block, 0, stream>>>(Q2, K2, c_2, u_2,
                                                   node_sum, num_edges);
    }

    // Node pass.
    {
        const int block = 256;
        const int grid = (num_nodes + block - 1) / block;
        pe_node_kernel<<<grid, block, 0, stream>>>(node_sum, batch, out,
                                                   num_nodes);
    }
}

// Round 2
// 312.280 us; speedup vs baseline: 1.1548x; 1.1548x over previous
//
#include <hip/hip_runtime.h>
#include <hip/hip_fp16.h>
#include <math.h>

// Pass 0: convert Q,K fp32 -> fp16 rows in d_ws. Values ~N(0,1): fp16 storage
// costs ~5e-4 rel error per element -> ~5e-3 abs on ell -> ~0.2 abs on E
// (threshold 34.56). Accumulation stays fp32.
__global__ __launch_bounds__(256) void pe_convert_kernel(
    const float* __restrict__ Q,
    const float* __restrict__ K,
    __half* __restrict__ Qh,
    __half* __restrict__ Kh,
    int n4) {  // n/4 float4 groups per array
    int i = blockIdx.x * blockDim.x + threadIdx.x;
    const int stride = gridDim.x * blockDim.x;
    for (; i < n4; i += stride) {
        float4 q = ((const float4*)Q)[i];
        float4 k = ((const float4*)K)[i];
        __half2 q01 = __floats2half2_rn(q.x, q.y);
        __half2 q23 = __floats2half2_rn(q.z, q.w);
        __half2 k01 = __floats2half2_rn(k.x, k.y);
        __half2 k23 = __floats2half2_rn(k.z, k.w);
        ((__half2*)Qh)[2 * i] = q01;
        ((__half2*)Qh)[2 * i + 1] = q23;
        ((__half2*)Kh)[2 * i] = k01;
        ((__half2*)Kh)[2 * i + 1] = k23;
    }
}

// Pass 1: 8 lanes per edge. Row = 64 halves = 128 B = 8 x float4. Lane sub
// loads float4 #sub of Q[c[e]] and K[u[e]] (fully coalesced 128 B segment),
// fp32-accumulates the partial dot, 3-step shfl_xor reduce, lane 0 atomicAdds
// exp(dot/8) into node_sum[c[e]].
__global__ __launch_bounds__(256) void pe_edge_kernel(
    const __half* __restrict__ Qh,
    const __half* __restrict__ Kh,
    const int* __restrict__ c,
    const int* __restrict__ u,
    float* __restrict__ node_sum,
    int num_edges) {
    const int tid = blockIdx.x * blockDim.x + threadIdx.x;
    const int group = tid >> 3;   // 8 lanes per edge
    const int sub = tid & 7;
    const int ngroups = (gridDim.x * blockDim.x) >> 3;
    const float inv_scale = 0.125f;  // 1/sqrt(64)

    for (int e = group; e < num_edges; e += ngroups) {
        const int ci = c[e];
        const int ui = u[e];
        const float4 qraw = ((const float4*)(Qh + (size_t)ci * 64))[sub];
        const float4 kraw = ((const float4*)(Kh + (size_t)ui * 64))[sub];
        const __half2* q2 = (const __half2*)&qraw;
        const __half2* k2 = (const __half2*)&kraw;
        float dot = 0.0f;
#pragma unroll
        for (int j = 0; j < 4; ++j) {
            float2 qf = __half22float2(q2[j]);
            float2 kf = __half22float2(k2[j]);
            dot = fmaf(qf.x, kf.x, dot);
            dot = fmaf(qf.y, kf.y, dot);
        }
        // reduce over the 8-lane group (xor masks < 8 stay in-group)
        dot += __shfl_xor(dot, 1, 64);
        dot += __shfl_xor(dot, 2, 64);
        dot += __shfl_xor(dot, 4, 64);
        if (sub == 0) {
            atomicAdd(&node_sum[ci], __expf(dot * inv_scale));
        }
    }
}

// Pass 2: lse = log(node_sum[n]) (0 for empty), segment-sum into out[batch[n]].
// batch is sorted -> wave-uniform fast path cuts atomics to ~1 per wave.
__global__ __launch_bounds__(256) void pe_node_kernel(
    const float* __restrict__ node_sum,
    const int* __restrict__ batch,
    float* __restrict__ out,
    int num_nodes) {
    const int n = blockIdx.x * blockDim.x + threadIdx.x;
    const bool valid = (n < num_nodes);
    const int nc = valid ? n : (num_nodes - 1);

    const float s = valid ? node_sum[nc] : 0.0f;
    float lse = (s > 0.0f) ? logf(s) : 0.0f;
    if (!valid) lse = 0.0f;
    const int b = batch[nc];

    const int b0 = __shfl(b, 0, 64);
    const bool uniform = __all(b == b0);
    if (uniform) {
        lse += __shfl_xor(lse, 1, 64);
        lse += __shfl_xor(lse, 2, 64);
        lse += __shfl_xor(lse, 4, 64);
        lse += __shfl_xor(lse, 8, 64);
        lse += __shfl_xor(lse, 16, 64);
        lse += __shfl_xor(lse, 32, 64);
        if ((threadIdx.x & 63) == 0 && lse != 0.0f) {
            atomicAdd(&out[b0], lse);
        }
    } else {
        if (valid && lse != 0.0f) {
            atomicAdd(&out[b], lse);
        }
    }
}

extern "C" void kernel_launch(void* const* d_in, const int* in_sizes, int n_in,
                              void* d_out, int out_size, void* d_ws, size_t ws_size,
                              hipStream_t stream) {
    const float* Q2 = (const float*)d_in[0];
    const float* K2 = (const float*)d_in[1];
    const int* c_2 = (const int*)d_in[2];
    const int* u_2 = (const int*)d_in[3];
    const int* batch = (const int*)d_in[4];

    const int num_nodes = in_sizes[4];   // batch: one entry per node
    const int num_edges = in_sizes[2];
    const int num_graphs = out_size;
    const int d = in_sizes[0] / num_nodes;   // 64
    const size_t row_elems = (size_t)num_nodes * d;

    // d_ws layout: Qh | Kh | node_sum   (fp16 rows 16B-aligned)
    __half* Qh = (__half*)d_ws;
    __half* Kh = Qh + row_elems;
    float* node_sum = (float*)(Kh + row_elems);
    float* out = (float*)d_out;

    hipMemsetAsync(node_sum, 0, (size_t)num_nodes * sizeof(float), stream);
    hipMemsetAsync(out, 0, (size_t)num_graphs * sizeof(float), stream);

    // Pass 0: fp32 -> fp16 (6.4M elements per array, float4-vectorized)
    {
        const int n4 = (int)(row_elems / 4);
        const int block = 256;
        const int grid = 2048;
        pe_convert_kernel<<<grid, block, 0, stream>>>(Q2, K2, Qh, Kh, n4);
    }

    // Pass 1: edge gather + exp + node atomic
    {
        const int block = 256;
        const int grid = 16384;
        pe_edge_kernel<<<grid, block, 0, stream>>>(Qh, Kh, c_2, u_2,
                                                   node_sum, num_edges);
    }

    // Pass 2: log + per-graph sum
    {
        const int block = 256;
        const int grid = (num_nodes + block - 1) / block;
        pe_node_kernel<<<grid, block, 0, stream>>>(node_sum, batch, out,
                                                   num_nodes);
    }
}

// Round 3
// 305.411 us; speedup vs baseline: 1.1808x; 1.0225x over previous
//
#include <hip/hip_runtime.h>
#include <hip/hip_fp16.h>
#include <math.h>

// Pass 0: convert Q,K fp32 -> fp16 rows in d_ws. Each thread handles 8 floats
// per array: 2x float4 loads -> 1x 16B store of 8 halves.
__global__ __launch_bounds__(256) void pe_convert_kernel(
    const float* __restrict__ Q,
    const float* __restrict__ K,
    __half* __restrict__ Qh,
    __half* __restrict__ Kh,
    int n8) {  // total elements / 8
    const int i = blockIdx.x * blockDim.x + threadIdx.x;
    if (i >= n8) return;
    float4 qa = ((const float4*)Q)[2 * i];
    float4 qb = ((const float4*)Q)[2 * i + 1];
    float4 ka = ((const float4*)K)[2 * i];
    float4 kb = ((const float4*)K)[2 * i + 1];
    __half2 qh[4], kh[4];
    qh[0] = __floats2half2_rn(qa.x, qa.y);
    qh[1] = __floats2half2_rn(qa.z, qa.w);
    qh[2] = __floats2half2_rn(qb.x, qb.y);
    qh[3] = __floats2half2_rn(qb.z, qb.w);
    kh[0] = __floats2half2_rn(ka.x, ka.y);
    kh[1] = __floats2half2_rn(ka.z, ka.w);
    kh[2] = __floats2half2_rn(kb.x, kb.y);
    kh[3] = __floats2half2_rn(kb.z, kb.w);
    ((float4*)Qh)[i] = *(float4*)qh;   // 16B store of 8 halves
    ((float4*)Kh)[i] = *(float4*)kh;
}

__device__ __forceinline__ float dot8h(const float4& qraw, const float4& kraw) {
    const __half2* q2 = (const __half2*)&qraw;
    const __half2* k2 = (const __half2*)&kraw;
    float dot = 0.0f;
#pragma unroll
    for (int j = 0; j < 4; ++j) {
        float2 qf = __half22float2(q2[j]);
        float2 kf = __half22float2(k2[j]);
        dot = fmaf(qf.x, kf.x, dot);
        dot = fmaf(qf.y, kf.y, dot);
    }
    return dot;
}

__device__ __forceinline__ float red8(float d) {
    d += __shfl_xor(d, 1, 64);
    d += __shfl_xor(d, 2, 64);
    d += __shfl_xor(d, 4, 64);
    return d;
}

// Pass 1: 8 lanes per edge, 4 edges per group-iteration. All 8 gather loads
// (4 edges x Q,K; each a coalesced 128B row segment) are issued back-to-back
// to get 8 outstanding lines per wave (latency hiding). After the butterfly
// reduction every lane of the group holds all 4 dots; lanes 0..3 each fire
// one atomic -> the 4 atomics per group share a single vmem instruction.
__global__ __launch_bounds__(256) void pe_edge_kernel(
    const __half* __restrict__ Qh,
    const __half* __restrict__ Kh,
    const int* __restrict__ c,
    const int* __restrict__ u,
    float* __restrict__ node_sum,
    int num_edges) {
    const int tid = blockIdx.x * blockDim.x + threadIdx.x;
    const int group = tid >> 3;
    const int sub = tid & 7;
    const int ngroups = (gridDim.x * blockDim.x) >> 3;
    const float inv_scale = 0.125f;  // 1/sqrt(64)

    const int E4 = num_edges & ~3;   // chunk-aligned portion

    for (int base = group * 4; base + 4 <= E4 + 4 && base + 3 < num_edges;
         base += ngroups * 4) {
        const int4 ci = *(const int4*)(c + base);
        const int4 ui = *(const int4*)(u + base);

        const float4* qp0 = (const float4*)(Qh + (size_t)ci.x * 64);
        const float4* qp1 = (const float4*)(Qh + (size_t)ci.y * 64);
        const float4* qp2 = (const float4*)(Qh + (size_t)ci.z * 64);
        const float4* qp3 = (const float4*)(Qh + (size_t)ci.w * 64);
        const float4* kp0 = (const float4*)(Kh + (size_t)ui.x * 64);
        const float4* kp1 = (const float4*)(Kh + (size_t)ui.y * 64);
        const float4* kp2 = (const float4*)(Kh + (size_t)ui.z * 64);
        const float4* kp3 = (const float4*)(Kh + (size_t)ui.w * 64);

        // issue all 8 gathers back-to-back
        const float4 q0 = qp0[sub];
        const float4 q1 = qp1[sub];
        const float4 q2 = qp2[sub];
        const float4 q3 = qp3[sub];
        const float4 k0 = kp0[sub];
        const float4 k1 = kp1[sub];
        const float4 k2 = kp2[sub];
        const float4 k3 = kp3[sub];

        float d0 = red8(dot8h(q0, k0));
        float d1 = red8(dot8h(q1, k1));
        float d2 = red8(dot8h(q2, k2));
        float d3 = red8(dot8h(q3, k3));

        // lanes 0..3 of the group each handle one edge's atomic
        const float dsel = (sub == 0) ? d0 : (sub == 1) ? d1 : (sub == 2) ? d2 : d3;
        const int csel = (sub == 0) ? ci.x : (sub == 1) ? ci.y : (sub == 2) ? ci.z : ci.w;
        if (sub < 4) {
            atomicAdd(&node_sum[csel], __expf(dsel * inv_scale));
        }
    }

    // tail (num_edges % 4 != 0): one edge per group
    for (int e = E4 + group; e < num_edges; e += ngroups) {
        const int cc = c[e];
        const int uu = u[e];
        const float4 q = ((const float4*)(Qh + (size_t)cc * 64))[sub];
        const float4 k = ((const float4*)(Kh + (size_t)uu * 64))[sub];
        float d = red8(dot8h(q, k));
        if (sub == 0) atomicAdd(&node_sum[cc], __expf(d * inv_scale));
    }
}

// Pass 2: lse = log(node_sum[n]) (0 for empty), segment-sum into out[batch[n]].
__global__ __launch_bounds__(256) void pe_node_kernel(
    const float* __restrict__ node_sum,
    const int* __restrict__ batch,
    float* __restrict__ out,
    int num_nodes) {
    const int n = blockIdx.x * blockDim.x + threadIdx.x;
    const bool valid = (n < num_nodes);
    const int nc = valid ? n : (num_nodes - 1);

    const float s = valid ? node_sum[nc] : 0.0f;
    float lse = (s > 0.0f) ? logf(s) : 0.0f;
    if (!valid) lse = 0.0f;
    const int b = batch[nc];

    const int b0 = __shfl(b, 0, 64);
    const bool uniform = __all(b == b0);
    if (uniform) {
        lse += __shfl_xor(lse, 1, 64);
        lse += __shfl_xor(lse, 2, 64);
        lse += __shfl_xor(lse, 4, 64);
        lse += __shfl_xor(lse, 8, 64);
        lse += __shfl_xor(lse, 16, 64);
        lse += __shfl_xor(lse, 32, 64);
        if ((threadIdx.x & 63) == 0 && lse != 0.0f) {
            atomicAdd(&out[b0], lse);
        }
    } else {
        if (valid && lse != 0.0f) {
            atomicAdd(&out[b], lse);
        }
    }
}

extern "C" void kernel_launch(void* const* d_in, const int* in_sizes, int n_in,
                              void* d_out, int out_size, void* d_ws, size_t ws_size,
                              hipStream_t stream) {
    const float* Q2 = (const float*)d_in[0];
    const float* K2 = (const float*)d_in[1];
    const int* c_2 = (const int*)d_in[2];
    const int* u_2 = (const int*)d_in[3];
    const int* batch = (const int*)d_in[4];

    const int num_nodes = in_sizes[4];
    const int num_edges = in_sizes[2];
    const int num_graphs = out_size;
    const int d = in_sizes[0] / num_nodes;   // 64
    const size_t row_elems = (size_t)num_nodes * d;

    __half* Qh = (__half*)d_ws;
    __half* Kh = Qh + row_elems;
    float* node_sum = (float*)(Kh + row_elems);
    float* out = (float*)d_out;

    hipMemsetAsync(node_sum, 0, (size_t)num_nodes * sizeof(float), stream);
    hipMemsetAsync(out, 0, (size_t)num_graphs * sizeof(float), stream);

    // Pass 0: fp32 -> fp16
    {
        const int n8 = (int)(row_elems / 8);
        const int block = 256;
        const int grid = (n8 + block - 1) / block;
        pe_convert_kernel<<<grid, block, 0, stream>>>(Q2, K2, Qh, Kh, n8);
    }

    // Pass 1: edge gather + exp + node atomic (8 lanes/edge, 4 edges/iter)
    {
        const int block = 256;
        const int grid = 8192;   // 262144 groups, ~3 chunks each
        pe_edge_kernel<<<grid, block, 0, stream>>>(Qh, Kh, c_2, u_2,
                                                   node_sum, num_edges);
    }

    // Pass 2: log + per-graph sum
    {
        const int block = 256;
        const int grid = (num_nodes + block - 1) / block;
        pe_node_kernel<<<grid, block, 0, stream>>>(node_sum, batch, out,
                                                   num_nodes);
    }
}

// Round 4
// 301.528 us; speedup vs baseline: 1.1960x; 1.0129x over previous
//
#include <hip/hip_runtime.h>
#include <hip/hip_fp8.h>
#include <math.h>

typedef __attribute__((ext_vector_type(2))) float fv2;

#if defined(__has_builtin)
#  if __has_builtin(__builtin_amdgcn_cvt_pk_f32_fp8) && \
      __has_builtin(__builtin_amdgcn_cvt_pk_fp8_f32)
#    define PE_HAVE_FP8_BUILTINS 1
#  endif
#endif

// pack 4 floats -> 4 fp8 e4m3 bytes in one uint32
__device__ __forceinline__ unsigned pack4_fp8(float a, float b, float c, float d) {
#ifdef PE_HAVE_FP8_BUILTINS
    int w = 0;
    w = __builtin_amdgcn_cvt_pk_fp8_f32(a, b, w, false);  // bytes 0,1
    w = __builtin_amdgcn_cvt_pk_fp8_f32(c, d, w, true);   // bytes 2,3
    return (unsigned)w;
#else
    unsigned r = 0;
    r |= (unsigned)__hip_fp8_e4m3(a).__x;
    r |= (unsigned)__hip_fp8_e4m3(b).__x << 8;
    r |= (unsigned)__hip_fp8_e4m3(c).__x << 16;
    r |= (unsigned)__hip_fp8_e4m3(d).__x << 24;
    return r;
#endif
}

// fp32 dot of two uint32s each holding 4 fp8 e4m3 values
__device__ __forceinline__ float dot4w_fp8(unsigned qa, unsigned ka, float acc) {
#ifdef PE_HAVE_FP8_BUILTINS
    fv2 q0 = __builtin_amdgcn_cvt_pk_f32_fp8((int)qa, false);
    fv2 q1 = __builtin_amdgcn_cvt_pk_f32_fp8((int)qa, true);
    fv2 k0 = __builtin_amdgcn_cvt_pk_f32_fp8((int)ka, false);
    fv2 k1 = __builtin_amdgcn_cvt_pk_f32_fp8((int)ka, true);
    acc = fmaf(q0.x, k0.x, acc);
    acc = fmaf(q0.y, k0.y, acc);
    acc = fmaf(q1.x, k1.x, acc);
    acc = fmaf(q1.y, k1.y, acc);
    return acc;
#else
#pragma unroll
    for (int j = 0; j < 4; ++j) {
        __hip_fp8_e4m3 qv, kv;
        qv.__x = (qa >> (8 * j)) & 0xff;
        kv.__x = (ka >> (8 * j)) & 0xff;
        acc = fmaf((float)qv, (float)kv, acc);
    }
    return acc;
#endif
}

// 16-byte (quarter-row) fp8 dot
__device__ __forceinline__ float dot16_fp8(const uint4& q, const uint4& k) {
    float d = 0.0f;
    d = dot4w_fp8(q.x, k.x, d);
    d = dot4w_fp8(q.y, k.y, d);
    d = dot4w_fp8(q.z, k.z, d);
    d = dot4w_fp8(q.w, k.w, d);
    return d;
}

__device__ __forceinline__ float red4(float d) {
    d += __shfl_xor(d, 1, 64);
    d += __shfl_xor(d, 2, 64);
    return d;
}

// Pass 0: fp32 -> fp8 e4m3 rows; also zeroes node_sum and out (fused memsets).
// Thread i converts 16 consecutive floats of each array (4x float4 loads ->
// one uint4 store).
__global__ __launch_bounds__(256) void pe_convert_kernel(
    const float* __restrict__ Q,
    const float* __restrict__ K,
    unsigned* __restrict__ Qq,   // row = 16 uints = 64 fp8
    unsigned* __restrict__ Kq,
    float* __restrict__ node_sum,
    float* __restrict__ out,
    int n16,          // total elements / 16
    int num_nodes,
    int num_graphs) {
    const int i = blockIdx.x * blockDim.x + threadIdx.x;
    if (i < num_nodes) node_sum[i] = 0.0f;
    if (i < num_graphs) out[i] = 0.0f;
    if (i >= n16) return;

    uint4 qw, kw;
    {
        float4 a = ((const float4*)Q)[4 * i + 0];
        float4 b = ((const float4*)Q)[4 * i + 1];
        float4 c = ((const float4*)Q)[4 * i + 2];
        float4 d = ((const float4*)Q)[4 * i + 3];
        qw.x = pack4_fp8(a.x, a.y, a.z, a.w);
        qw.y = pack4_fp8(b.x, b.y, b.z, b.w);
        qw.z = pack4_fp8(c.x, c.y, c.z, c.w);
        qw.w = pack4_fp8(d.x, d.y, d.z, d.w);
    }
    {
        float4 a = ((const float4*)K)[4 * i + 0];
        float4 b = ((const float4*)K)[4 * i + 1];
        float4 c = ((const float4*)K)[4 * i + 2];
        float4 d = ((const float4*)K)[4 * i + 3];
        kw.x = pack4_fp8(a.x, a.y, a.z, a.w);
        kw.y = pack4_fp8(b.x, b.y, b.z, b.w);
        kw.z = pack4_fp8(c.x, c.y, c.z, c.w);
        kw.w = pack4_fp8(d.x, d.y, d.z, d.w);
    }
    ((uint4*)Qq)[i] = qw;
    ((uint4*)Kq)[i] = kw;
}

// Pass 1: 4 lanes per edge (row = 64 fp8 = 64 B = exactly ONE cache line;
// lane sub reads uint4 #sub). 4 edges per group-iteration: 8 gather loads
// issued per iter, and after the 2-step butterfly every lane of the group
// holds all 4 dots -> each of the 4 lanes fires one edge's atomic, so ALL 64
// lanes of the wave participate in a single atomic instruction (64 edges).
__global__ __launch_bounds__(256) void pe_edge_kernel(
    const unsigned* __restrict__ Qq,
    const unsigned* __restrict__ Kq,
    const int* __restrict__ c,
    const int* __restrict__ u,
    float* __restrict__ node_sum,
    int num_edges) {
    const int tid = blockIdx.x * blockDim.x + threadIdx.x;
    const int group = tid >> 2;
    const int sub = tid & 3;
    const int ngroups = (gridDim.x * blockDim.x) >> 2;
    const float inv_scale = 0.125f;  // 1/sqrt(64)

    const int E4 = num_edges & ~3;

    for (int base = group * 4; base < E4; base += ngroups * 4) {
        const int4 ci = *(const int4*)(c + base);
        const int4 ui = *(const int4*)(u + base);

        const uint4 q0 = *(const uint4*)(Qq + (size_t)ci.x * 16 + sub * 4);
        const uint4 q1 = *(const uint4*)(Qq + (size_t)ci.y * 16 + sub * 4);
        const uint4 q2 = *(const uint4*)(Qq + (size_t)ci.z * 16 + sub * 4);
        const uint4 q3 = *(const uint4*)(Qq + (size_t)ci.w * 16 + sub * 4);
        const uint4 k0 = *(const uint4*)(Kq + (size_t)ui.x * 16 + sub * 4);
        const uint4 k1 = *(const uint4*)(Kq + (size_t)ui.y * 16 + sub * 4);
        const uint4 k2 = *(const uint4*)(Kq + (size_t)ui.z * 16 + sub * 4);
        const uint4 k3 = *(const uint4*)(Kq + (size_t)ui.w * 16 + sub * 4);

        float d0 = red4(dot16_fp8(q0, k0));
        float d1 = red4(dot16_fp8(q1, k1));
        float d2 = red4(dot16_fp8(q2, k2));
        float d3 = red4(dot16_fp8(q3, k3));

        const float dsel = (sub == 0) ? d0 : (sub == 1) ? d1 : (sub == 2) ? d2 : d3;
        const int csel = (sub == 0) ? ci.x : (sub == 1) ? ci.y : (sub == 2) ? ci.z : ci.w;
        atomicAdd(&node_sum[csel], __expf(dsel * inv_scale));
    }

    // tail (num_edges % 4): one edge per group
    for (int e = E4 + group; e < num_edges; e += ngroups) {
        const int cc = c[e];
        const int uu = u[e];
        const uint4 q = *(const uint4*)(Qq + (size_t)cc * 16 + sub * 4);
        const uint4 k = *(const uint4*)(Kq + (size_t)uu * 16 + sub * 4);
        float d = red4(dot16_fp8(q, k));
        if (sub == 0) atomicAdd(&node_sum[cc], __expf(d * inv_scale));
    }
}

// Pass 2: lse = log(node_sum[n]) (0 for empty), segment-sum into out[batch[n]].
__global__ __launch_bounds__(256) void pe_node_kernel(
    const float* __restrict__ node_sum,
    const int* __restrict__ batch,
    float* __restrict__ out,
    int num_nodes) {
    const int n = blockIdx.x * blockDim.x + threadIdx.x;
    const bool valid = (n < num_nodes);
    const int nc = valid ? n : (num_nodes - 1);

    const float s = valid ? node_sum[nc] : 0.0f;
    float lse = (s > 0.0f) ? logf(s) : 0.0f;
    if (!valid) lse = 0.0f;
    const int b = batch[nc];

    const int b0 = __shfl(b, 0, 64);
    const bool uniform = __all(b == b0);
    if (uniform) {
        lse += __shfl_xor(lse, 1, 64);
        lse += __shfl_xor(lse, 2, 64);
        lse += __shfl_xor(lse, 4, 64);
        lse += __shfl_xor(lse, 8, 64);
        lse += __shfl_xor(lse, 16, 64);
        lse += __shfl_xor(lse, 32, 64);
        if ((threadIdx.x & 63) == 0 && lse != 0.0f) {
            atomicAdd(&out[b0], lse);
        }
    } else {
        if (valid && lse != 0.0f) {
            atomicAdd(&out[b], lse);
        }
    }
}

extern "C" void kernel_launch(void* const* d_in, const int* in_sizes, int n_in,
                              void* d_out, int out_size, void* d_ws, size_t ws_size,
                              hipStream_t stream) {
    const float* Q2 = (const float*)d_in[0];
    const float* K2 = (const float*)d_in[1];
    const int* c_2 = (const int*)d_in[2];
    const int* u_2 = (const int*)d_in[3];
    const int* batch = (const int*)d_in[4];

    const int num_nodes = in_sizes[4];
    const int num_edges = in_sizes[2];
    const int num_graphs = out_size;
    const int d = in_sizes[0] / num_nodes;   // 64
    const size_t row_elems = (size_t)num_nodes * d;

    // d_ws layout: Qq (row_elems fp8) | Kq (row_elems fp8) | node_sum (fp32)
    unsigned* Qq = (unsigned*)d_ws;
    unsigned* Kq = Qq + row_elems / 4;       // row_elems bytes
    float* node_sum = (float*)(Kq + row_elems / 4);
    float* out = (float*)d_out;

    // Pass 0: fp32 -> fp8 + fused zeroing of node_sum/out
    {
        const int n16 = (int)(row_elems / 16);
        const int block = 256;
        const int grid = (n16 + block - 1) / block;   // covers num_nodes too
        pe_convert_kernel<<<grid, block, 0, stream>>>(Q2, K2, Qq, Kq,
                                                      node_sum, out,
                                                      n16, num_nodes, num_graphs);
    }

    // Pass 1: edge gather + exp + node atomic (4 lanes/edge, 4 edges/iter)
    {
        const int block = 256;
        const int grid = 8192;
        pe_edge_kernel<<<grid, block, 0, stream>>>(Qq, Kq, c_2, u_2,
                                                   node_sum, num_edges);
    }

    // Pass 2: log + per-graph sum
    {
        const int block = 256;
        const int grid = (num_nodes + block - 1) / block;
        pe_node_kernel<<<grid, block, 0, stream>>>(node_sum, batch, out,
                                                   num_nodes);
    }
}